// Round 9
// baseline (508.879 us; speedup 1.0000x reference)
//
#include <hip/hip_runtime.h>

#define NN   8192
#define DEG  16
#define HID  128
#define IND  128
#define ED   8
#define NBLK 256

typedef __bf16 bf16_t;
typedef __bf16 bf16x8 __attribute__((ext_vector_type(8)));
typedef float  f32x4  __attribute__((ext_vector_type(4)));
typedef float  f32x2  __attribute__((ext_vector_type(2)));
typedef unsigned long long u64;
typedef u64 u64x2 __attribute__((ext_vector_type(2)));

static __device__ __forceinline__ f32x4 mfma16(bf16x8 a, bf16x8 b, f32x4 c) {
  return __builtin_amdgcn_mfma_f32_16x16x32_bf16(a, b, c, 0, 0, 0);
}
static __device__ __forceinline__ unsigned short bfbits(bf16_t x) {
  return __builtin_bit_cast(unsigned short, x);
}
static __device__ __forceinline__ bf16_t bits2bf(unsigned short x) {
  return __builtin_bit_cast(bf16_t, x);
}
// LDS-phase barrier: drain LDS ops only -- global loads/stores stay in flight.
static __device__ __forceinline__ void bar_lds() {
  __builtin_amdgcn_sched_barrier(0);
  asm volatile("s_waitcnt lgkmcnt(0)" ::: "memory");
  __builtin_amdgcn_s_barrier();
  __builtin_amdgcn_sched_barrier(0);
}

// ---------------- kernel 1: h0 = x @ Wp + bp ; init sync state ----------------
__global__ __launch_bounds__(128) void k_h0(const float* __restrict__ x,
                                            const float* __restrict__ Wp,
                                            const float* __restrict__ bp,
                                            float* __restrict__ h,
                                            bf16_t* __restrict__ h2hi,
                                            int* __restrict__ flags, int fs,
                                            int sent) {
  __shared__ float sx[8][IND];
  const int t  = threadIdx.x;      // 0..127 = output channel
  const int vb = blockIdx.x * 8;   // 8 nodes per block
  #pragma unroll
  for (int rr = 0; rr < 8; ++rr) sx[rr][t] = x[(size_t)(vb + rr) * IND + t];
  __syncthreads();
  float acc[8];
  const float bias = bp[t];
  #pragma unroll
  for (int rr = 0; rr < 8; ++rr) acc[rr] = bias;
  for (int k = 0; k < IND; ++k) {
    const float w = Wp[k * HID + t];
    #pragma unroll
    for (int rr = 0; rr < 8; ++rr) acc[rr] += sx[rr][k] * w;
  }
  #pragma unroll
  for (int rr = 0; rr < 8; ++rr) h[(size_t)(vb + rr) * HID + t] = acc[rr];
  if (sent) {
    // hi plane: row 0 = bf16 of h0 (node 0 final); rows >=1 = 0xFFFF sentinel
    #pragma unroll
    for (int rr = 0; rr < 8; ++rr) {
      unsigned short hw = 0xFFFFu;
      if (vb + rr == 0) hw = bfbits((bf16_t)acc[rr]);
      h2hi[(size_t)(vb + rr) * HID + t] = bits2bf(hw);
    }
  } else if (t < 8) {
    flags[(vb + t) * fs] = (vb + t == 0) ? 0xF : 0;
  }
}

// ---------------- kernel 2: persistent DAG executor ----------------
// 256 blocks (1/CU), 4 waves, each wave owns two ADJACENT channels per lane
// (cc = wid*32+2r, +1). Sync channel = planar bf16-hi rows: gathered 16B
// chunks ARE the MFMA A-fragments; sentinel = bf16 sign bits. fp32 output
// written directly at publish (plain store, off sync path) -- no tail.
// All on-chain MFMA phases use depth-1 accumulator chains.
#define LOAD_WFRAGS(W, KROWS, NKK, ARRH, ARRL)                                \
  _Pragma("unroll")                                                           \
  for (int n = 0; n < 2; ++n) {                                               \
    _Pragma("unroll")                                                         \
    for (int kk = 0; kk < NKK; ++kk) {                                        \
      _Pragma("unroll")                                                       \
      for (int i = 0; i < 8; ++i) {                                           \
        const int k = kk * 32 + g * 8 + i;                                    \
        const float w = (k < KROWS) ? W[k * HID + cc[n]] : 0.f;               \
        const bf16_t wh = (bf16_t)w;                                          \
        ARRH[n][kk][i] = wh;                                                  \
        ARRL[n][kk][i] = (bf16_t)(w - (float)wh);                             \
      }                                                                       \
    }                                                                         \
  }
#define LOAD_WFRAGS_H(W, KROWS, NKK, ARRH)                                    \
  _Pragma("unroll")                                                           \
  for (int n = 0; n < 2; ++n) {                                               \
    _Pragma("unroll")                                                         \
    for (int kk = 0; kk < NKK; ++kk) {                                        \
      _Pragma("unroll")                                                       \
      for (int i = 0; i < 8; ++i) {                                           \
        const int k = kk * 32 + g * 8 + i;                                    \
        const float w = (k < KROWS) ? W[k * HID + cc[n]] : 0.f;               \
        ARRH[n][kk][i] = (bf16_t)w;                                           \
      }                                                                       \
    }                                                                         \
  }
#define LOAD_WFRAGS_L(W, KROWS, NKK, ARRL)                                    \
  _Pragma("unroll")                                                           \
  for (int n = 0; n < 2; ++n) {                                               \
    _Pragma("unroll")                                                         \
    for (int kk = 0; kk < NKK; ++kk) {                                        \
      _Pragma("unroll")                                                       \
      for (int i = 0; i < 8; ++i) {                                           \
        const int k = kk * 32 + g * 8 + i;                                    \
        const float w = (k < KROWS) ? W[k * HID + cc[n]] : 0.f;               \
        ARRL[n][kk][i] = (bf16_t)(w - (float)(bf16_t)w);                      \
      }                                                                       \
    }                                                                         \
  }

// SENT gather: 8 u64 relaxed-atomic loads of the hi plane (lane's quarter row)
#define LOADQH()                                                              \
  _Pragma("unroll")                                                           \
  for (int kk = 0; kk < 4; ++kk) {                                            \
    _Pragma("unroll")                                                         \
    for (int u = 0; u < 2; ++u)                                               \
      q[kk * 2 + u] = __hip_atomic_load(hp + kk * 8 + u, __ATOMIC_RELAXED,    \
                                        __HIP_MEMORY_SCOPE_AGENT);            \
  }

#define ZERO4(a) { a[0][0]=0.f;a[0][1]=0.f;a[0][2]=0.f;a[0][3]=0.f; a[1]=a[0]; }
#define BIAS4(a, b) { a[0][0]=b[0];a[0][1]=b[0];a[0][2]=b[0];a[0][3]=b[0];    \
                      a[1][0]=b[1];a[1][1]=b[1];a[1][2]=b[1];a[1][3]=b[1]; }

template <bool SENT>
__global__ __launch_bounds__(256, 1) void k_dag(
    const int* __restrict__ ei, const float* __restrict__ attr,
    const float* __restrict__ Wm1, const float* __restrict__ bm1,
    const float* __restrict__ Wm2, const float* __restrict__ bm2,
    const float* __restrict__ Wu1, const float* __restrict__ bu1,
    const float* __restrict__ Wu2, const float* __restrict__ bu2,
    float* __restrict__ h, bf16_t* __restrict__ h2hi,
    int* __restrict__ flags, int fs) {
  const int tid  = threadIdx.x;
  const int lane = tid & 63;
  const int g    = lane >> 4;   // 16-lane group: k-block of A/B operands
  const int r    = lane & 15;   // A-row / B-col within tile
  const int wid  = tid >> 6;    // wave 0..3

  __shared__ bf16_t s_m1[16 * HID];            // msg1 acts, chunk-XOR swizzled
  __shared__ alignas(16) bf16_t s_agg[HID];    // bf16: read directly as frags
  __shared__ alignas(16) bf16_t s_u1[HID];

  int cc[2];                     // two ADJACENT channels per lane
  cc[0] = wid * 32 + 2 * r;
  cc[1] = cc[0] + 1;

  // ---- register-resident weight fragments ----
  bf16x8 wm1h[2][5], wm1l[2][5];          // m1: hi + weight-lo
  bf16x8 wm2h[2][4];                      // m2: hi only
  bf16x8 wu1h[2][8], wu1l[2][4];          // u1: lo only for h-half (kk 0..3)
  bf16x8 wu2h[2][4], wu2l[2][4];          // u2: hi/lo
  LOAD_WFRAGS(Wm1, 136, 5, wm1h, wm1l)    // rows 0..127 = h, 128..135 = attr
  LOAD_WFRAGS_H(Wm2, 128, 4, wm2h)
  LOAD_WFRAGS_H(Wu1, 256, 8, wu1h)
  LOAD_WFRAGS_L(Wu1, 128, 4, wu1l)
  LOAD_WFRAGS(Wu2, 128, 4, wu2h, wu2l)
  float bs_m1[2], bs_m2[2], bs_u1[2], bs_u2[2];
  #pragma unroll
  for (int n = 0; n < 2; ++n) {
    bs_m1[n] = bm1[cc[n]]; bs_m2[n] = bm2[cc[n]];
    bs_u1[n] = bu1[cc[n]]; bs_u2[n] = bu2[cc[n]];
  }

  const int v0 = 1 + (int)blockIdx.x;
  int s_cur = (v0 < NN) ? ei[(v0 - 1) * DEG + r] : 0;

  for (int v = v0; v < NN; v += NBLK) {
    // ---- poll/gather loads issue FIRST (minimize detect phase delay) ----
    u64 q[16];  // SENT uses [0..7] (hi plane); fallback uses all 16 (fp32 row)
    const u64* hp;
    if constexpr (SENT) {
      hp = (const u64*)(h2hi + (size_t)s_cur * HID) + g * 2;  // 32 u64/row
      LOADQH();
    } else {
      hp = (const u64*)(h + (size_t)s_cur * HID) + g * 4;
      #pragma unroll
      for (int kk = 0; kk < 4; ++kk)
        #pragma unroll
        for (int u = 0; u < 4; ++u)
          q[kk * 4 + u] = __hip_atomic_load(hp + kk * 16 + u, __ATOMIC_RELAXED,
                                            __HIP_MEMORY_SCOPE_AGENT);
    }

    // ---- off-chain: next edge list, own h0 row -> fragments, attr frag ----
    const int vn = (v + NBLK < NN) ? v + NBLK : v;
    const int s_nxt = ei[(vn - 1) * DEG + r];

    bf16x8 hvh[4], hvl[4];
    {
      const float* hvp = h + (size_t)v * HID + g * 8;
      #pragma unroll
      for (int kk = 0; kk < 4; ++kk) {
        const f32x4 p0 = *(const f32x4*)(hvp + kk * 32);
        const f32x4 p1 = *(const f32x4*)(hvp + kk * 32 + 4);
        #pragma unroll
        for (int i = 0; i < 4; ++i) {
          const float f0 = p0[i], f1 = p1[i];
          const bf16_t f0h = (bf16_t)f0, f1h = (bf16_t)f1;
          hvh[kk][i]     = f0h; hvl[kk][i]     = (bf16_t)(f0 - (float)f0h);
          hvh[kk][4 + i] = f1h; hvl[kk][4 + i] = (bf16_t)(f1 - (float)f1h);
        }
      }
    }
    bf16x8 a4h;
    #pragma unroll
    for (int i = 0; i < 8; ++i) a4h[i] = (bf16_t)0.f;
    if (g == 0) {
      const f32x4* ap = (const f32x4*)(attr + ((size_t)(v - 1) * DEG + r) * ED);
      const f32x4 a0 = ap[0], a1 = ap[1];
      #pragma unroll
      for (int i = 0; i < 4; ++i) {
        a4h[i] = (bf16_t)a0[i]; a4h[4 + i] = (bf16_t)a1[i];
      }
    }

    // ---- off-chain MFMA work overlapping the in-flight poll loads ----
    // (a) u1 h0_v-half (hi + weight-lo + act-lo; off-chain so depth is free)
    f32x4 uA[2], uB[2], uC[2], uD[2];
    BIAS4(uA, bs_u1) ZERO4(uB) ZERO4(uC) ZERO4(uD)
    #pragma unroll
    for (int kk = 0; kk < 4; ++kk) {
      #pragma unroll
      for (int n = 0; n < 2; ++n) {
        uA[n] = mfma16(hvh[kk], wu1h[n][kk], uA[n]);
        uB[n] = mfma16(hvh[kk], wu1l[n][kk], uB[n]);
        uC[n] = mfma16(hvl[kk], wu1h[n][kk], uC[n]);
      }
    }
    // (b) m1 init + attr k-step (independent of preds); 8 accumulators so the
    // post-detect pred k-steps are all depth-1
    f32x4 mA[2], mB[2], mC[2], mD[2], mE[2], mF[2], mG[2], mH[2];
    BIAS4(mA, bs_m1) ZERO4(mB) ZERO4(mC) ZERO4(mD)
    ZERO4(mE) ZERO4(mF) ZERO4(mG) ZERO4(mH)
    #pragma unroll
    for (int n = 0; n < 2; ++n) {
      mA[n] = mfma16(a4h, wm1h[n][4], mA[n]);
      mB[n] = mfma16(a4h, wm1l[n][4], mB[n]);
    }

    // ---- spin: data IS the sync (bf16 sign bits = sentinel) ----
    if constexpr (SENT) {
      bool ok = false;
      int guard = 0;
      for (;;) {
        if (!ok) {
          u64 m = 0;
          #pragma unroll
          for (int i = 0; i < 8; ++i) m |= q[i];
          ok = (s_cur == 0) || ((m & 0x8000800080008000ull) == 0);
        }
        if (__all(ok)) break;
        if (++guard > (1 << 13)) break;  // fail-safe: wrong answer, never hang
        if (!ok) LOADQH();
      }
    } else {
      const int* fp = flags + s_cur * fs;
      int fw = __hip_atomic_load(fp, __ATOMIC_RELAXED, __HIP_MEMORY_SCOPE_AGENT);
      int guard = 0;
      while (fw != 0xF && ++guard < (1 << 15)) {
        __builtin_amdgcn_s_sleep(1);
        fw = __hip_atomic_load(fp, __ATOMIC_RELAXED, __HIP_MEMORY_SCOPE_AGENT);
      }
      asm volatile("" ::: "memory");
      #pragma unroll
      for (int kk = 0; kk < 4; ++kk)
        #pragma unroll
        for (int u = 0; u < 4; ++u)
          q[kk * 4 + u] = __hip_atomic_load(hp + kk * 16 + u, __ATOMIC_RELAXED,
                                            __HIP_MEMORY_SCOPE_AGENT);
    }

    // ---- A fragments: SENT = loaded 16B chunks verbatim (zero unpack) ----
    bf16x8 ah[4];
    #pragma unroll
    for (int kk = 0; kk < 4; ++kk) {
      if constexpr (SENT) {
        u64x2 t2; t2[0] = q[kk * 2]; t2[1] = q[kk * 2 + 1];
        ah[kk] = __builtin_bit_cast(bf16x8, t2);
      } else {
        #pragma unroll
        for (int u = 0; u < 4; ++u)
          #pragma unroll
          for (int b = 0; b < 2; ++b)
            ah[kk][u * 2 + b] =
                (bf16_t)__uint_as_float((unsigned)(q[kk * 4 + u] >> (32 * b)));
      }
    }

    // ---- msg layer 1: 4 pred k-steps x (hi, weight-lo), ALL depth-1 ----
    f32x4 m1[2];
    #pragma unroll
    for (int n = 0; n < 2; ++n) {
      mA[n] = mfma16(ah[0], wm1h[n][0], mA[n]);
      mB[n] = mfma16(ah[1], wm1h[n][1], mB[n]);
      mC[n] = mfma16(ah[2], wm1h[n][2], mC[n]);
      mD[n] = mfma16(ah[3], wm1h[n][3], mD[n]);
      mE[n] = mfma16(ah[0], wm1l[n][0], mE[n]);
      mF[n] = mfma16(ah[1], wm1l[n][1], mF[n]);
      mG[n] = mfma16(ah[2], wm1l[n][2], mG[n]);
      mH[n] = mfma16(ah[3], wm1l[n][3], mH[n]);
    }
    #pragma unroll
    for (int n = 0; n < 2; ++n)
      m1[n] = ((mA[n] + mB[n]) + (mC[n] + mD[n])) +
              ((mE[n] + mF[n]) + (mG[n] + mH[n]));
    // relu -> bf16 -> LDS with chunk-XOR swizzle (conflict-free b128 reads)
    #pragma unroll
    for (int n = 0; n < 2; ++n) {
      const int c = cc[n], ch16 = c >> 3;
      #pragma unroll
      for (int reg = 0; reg < 4; ++reg) {
        const int j = g * 4 + reg;  // edge row (D layout: row = 4*(lane>>4)+reg)
        s_m1[j * HID + ((ch16 ^ j) * 8) + (c & 7)] = (bf16_t)fmaxf(m1[n][reg], 0.f);
      }
    }
    if constexpr (SENT) bar_lds(); else __syncthreads();   // B1

    // ---- msg layer 2 (hi-only, depth-1) + mean aggregation ----
    f32x4 m2[2];
    {
      f32x4 aA[2], aB[2], aC[2], aD[2];
      BIAS4(aA, bs_m2) ZERO4(aB) ZERO4(aC) ZERO4(aD)
      const bf16x8 a0 = *(const bf16x8*)(s_m1 + r * HID + (((0 * 4 + g) ^ r) * 8));
      const bf16x8 a1 = *(const bf16x8*)(s_m1 + r * HID + (((1 * 4 + g) ^ r) * 8));
      const bf16x8 a2 = *(const bf16x8*)(s_m1 + r * HID + (((2 * 4 + g) ^ r) * 8));
      const bf16x8 a3 = *(const bf16x8*)(s_m1 + r * HID + (((3 * 4 + g) ^ r) * 8));
      #pragma unroll
      for (int n = 0; n < 2; ++n) {
        aA[n] = mfma16(a0, wm2h[n][0], aA[n]);
        aB[n] = mfma16(a1, wm2h[n][1], aB[n]);
        aC[n] = mfma16(a2, wm2h[n][2], aC[n]);
        aD[n] = mfma16(a3, wm2h[n][3], aD[n]);
      }
      #pragma unroll
      for (int n = 0; n < 2; ++n) m2[n] = (aA[n] + aB[n]) + (aC[n] + aD[n]);
    }
    #pragma unroll
    for (int n = 0; n < 2; ++n) {
      float s = fmaxf(m2[n][0],0.f)+fmaxf(m2[n][1],0.f)+fmaxf(m2[n][2],0.f)+fmaxf(m2[n][3],0.f);
      s += __shfl_xor(s, 16, 64);
      s += __shfl_xor(s, 32, 64);
      if (lane < 16) s_agg[cc[n]] = (bf16_t)(s * 0.0625f);  // bf16 once
    }
    if constexpr (SENT) bar_lds(); else __syncthreads();   // B2

    // ---- update layer 1, agg-half (hi-only, depth-1: kk4..7 -> uA..uD) ----
    f32x4 u1v[2];
    {
      const bf16x8 A0 = *(const bf16x8*)(s_agg + 0 * 32 + g * 8);
      const bf16x8 A1 = *(const bf16x8*)(s_agg + 1 * 32 + g * 8);
      const bf16x8 A2 = *(const bf16x8*)(s_agg + 2 * 32 + g * 8);
      const bf16x8 A3 = *(const bf16x8*)(s_agg + 3 * 32 + g * 8);
      #pragma unroll
      for (int n = 0; n < 2; ++n) {
        uA[n] = mfma16(A0, wu1h[n][4], uA[n]);
        uB[n] = mfma16(A1, wu1h[n][5], uB[n]);
        uC[n] = mfma16(A2, wu1h[n][6], uC[n]);
        uD[n] = mfma16(A3, wu1h[n][7], uD[n]);
      }
    }
    #pragma unroll
    for (int n = 0; n < 2; ++n)
      u1v[n] = (uA[n] + uB[n]) + (uC[n] + uD[n]);
    if (lane < 16) {
      s_u1[cc[0]] = (bf16_t)fmaxf(u1v[0][0], 0.f);
      s_u1[cc[1]] = (bf16_t)fmaxf(u1v[1][0], 0.f);
    }
    if constexpr (SENT) bar_lds(); else __syncthreads();   // B3

    // ---- update layer 2 (hi + weight-lo, depth-1) -> publish ----
    f32x4 u2v[2];
    {
      f32x4 aA[2], aB[2], aC[2], aD[2], aE[2], aF[2], aG[2], aH[2];
      BIAS4(aA, bs_u2) ZERO4(aB) ZERO4(aC) ZERO4(aD)
      ZERO4(aE) ZERO4(aF) ZERO4(aG) ZERO4(aH)
      const bf16x8 A0 = *(const bf16x8*)(s_u1 + 0 * 32 + g * 8);
      const bf16x8 A1 = *(const bf16x8*)(s_u1 + 1 * 32 + g * 8);
      const bf16x8 A2 = *(const bf16x8*)(s_u1 + 2 * 32 + g * 8);
      const bf16x8 A3 = *(const bf16x8*)(s_u1 + 3 * 32 + g * 8);
      #pragma unroll
      for (int n = 0; n < 2; ++n) {
        aA[n] = mfma16(A0, wu2h[n][0], aA[n]);
        aB[n] = mfma16(A1, wu2h[n][1], aB[n]);
        aC[n] = mfma16(A2, wu2h[n][2], aC[n]);
        aD[n] = mfma16(A3, wu2h[n][3], aD[n]);
        aE[n] = mfma16(A0, wu2l[n][0], aE[n]);
        aF[n] = mfma16(A1, wu2l[n][1], aF[n]);
        aG[n] = mfma16(A2, wu2l[n][2], aG[n]);
        aH[n] = mfma16(A3, wu2l[n][3], aH[n]);
      }
      #pragma unroll
      for (int n = 0; n < 2; ++n)
        u2v[n] = ((aA[n] + aB[n]) + (aC[n] + aD[n])) +
                 ((aE[n] + aF[n]) + (aG[n] + aH[n]));
    }
    if (lane < 16) {  // D row 0 (all rows identical)
      const float r0 = fabsf(fmaxf(u2v[0][0], 0.f));  // fabs: kill -0.0
      const float r1 = fabsf(fmaxf(u2v[1][0], 0.f));
      if constexpr (SENT) {
        // hi-plane sync store FIRST (it gates consumers)
        const unsigned hiw = (unsigned)bfbits((bf16_t)r0) |
                             ((unsigned)bfbits((bf16_t)r1) << 16);
        __hip_atomic_store((unsigned*)h2hi + (size_t)v * (HID / 2) + wid * 16 + r,
                           hiw, __ATOMIC_RELAXED, __HIP_MEMORY_SCOPE_AGENT);
        // fp32 output store (plain, off the sync path; no one reads row v
        // before this block's own pre-read, which happened this iteration)
        f32x2 out2; out2[0] = r0; out2[1] = r1;
        *(f32x2*)&h[(size_t)v * HID + cc[0]] = out2;
      } else {
        __hip_atomic_store(&h[(size_t)v * HID + cc[0]], r0,
                           __ATOMIC_RELAXED, __HIP_MEMORY_SCOPE_AGENT);
        __hip_atomic_store(&h[(size_t)v * HID + cc[1]], r1,
                           __ATOMIC_RELAXED, __HIP_MEMORY_SCOPE_AGENT);
      }
    }
    if constexpr (!SENT) {
      if (lane == 0)
        __hip_atomic_fetch_or(&flags[v * fs], 1 << wid, __ATOMIC_RELEASE,
                              __HIP_MEMORY_SCOPE_AGENT);
    }
    s_cur = s_nxt;
    if constexpr (!SENT) __syncthreads();
  }
}

extern "C" void kernel_launch(void* const* d_in, const int* in_sizes, int n_in,
                              void* d_out, int out_size, void* d_ws, size_t ws_size,
                              hipStream_t stream) {
  const float* x    = (const float*)d_in[0];
  const int*   ei   = (const int*)  d_in[1];   // [2, E] int32; row 0 = src
  const float* attr = (const float*)d_in[2];
  const float* Wp   = (const float*)d_in[3];
  const float* bp   = (const float*)d_in[4];
  const float* Wm1  = (const float*)d_in[5];
  const float* bm1  = (const float*)d_in[6];
  const float* Wm2  = (const float*)d_in[7];
  const float* bm2  = (const float*)d_in[8];
  const float* Wu1  = (const float*)d_in[9];
  const float* bu1  = (const float*)d_in[10];
  const float* Wu2  = (const float*)d_in[11];
  const float* bu2  = (const float*)d_in[12];
  float* h = (float*)d_out;   // h state lives directly in d_out

  const size_t plane = (size_t)NN * HID * sizeof(bf16_t);   // 2 MB
  const bool sent = ws_size >= plane;
  bf16_t* h2hi = (bf16_t*)d_ws;
  int* flags   = (int*)d_ws;
  const int fs = sent ? 0 : ((ws_size >= (size_t)NN * 64 + 64) ? 16 : 1);

  k_h0<<<NN / 8, 128, 0, stream>>>(x, Wp, bp, h, h2hi, flags, fs, sent ? 1 : 0);
  if (sent)
    k_dag<true><<<NBLK, 256, 0, stream>>>(ei, attr, Wm1, bm1, Wm2, bm2,
                                          Wu1, bu1, Wu2, bu2, h, h2hi,
                                          flags, fs);
  else
    k_dag<false><<<NBLK, 256, 0, stream>>>(ei, attr, Wm1, bm1, Wm2, bm2,
                                           Wu1, bu1, Wu2, bu2, h, h2hi,
                                           flags, fs);
}

// Round 10
// 445.464 us; speedup vs baseline: 1.1424x; 1.1424x over previous
//
#include <hip/hip_runtime.h>

#define NN   8192
#define DEG  16
#define HID  128
#define IND  128
#define ED   8
#define NBLK 256

typedef __bf16 bf16_t;
typedef __bf16 bf16x8 __attribute__((ext_vector_type(8)));
typedef float  f32x4  __attribute__((ext_vector_type(4)));
typedef float  f32x2  __attribute__((ext_vector_type(2)));
typedef unsigned long long u64;
typedef u64 u64x2 __attribute__((ext_vector_type(2)));

static __device__ __forceinline__ f32x4 mfma16(bf16x8 a, bf16x8 b, f32x4 c) {
  return __builtin_amdgcn_mfma_f32_16x16x32_bf16(a, b, c, 0, 0, 0);
}
static __device__ __forceinline__ unsigned short bfbits(bf16_t x) {
  return __builtin_bit_cast(unsigned short, x);
}
static __device__ __forceinline__ bf16_t bits2bf(unsigned short x) {
  return __builtin_bit_cast(bf16_t, x);
}
// LDS-phase barrier: drain LDS ops only -- global loads/stores stay in flight.
static __device__ __forceinline__ void bar_lds() {
  __builtin_amdgcn_sched_barrier(0);
  asm volatile("s_waitcnt lgkmcnt(0)" ::: "memory");
  __builtin_amdgcn_s_barrier();
  __builtin_amdgcn_sched_barrier(0);
}

// ---------------- kernel 1: h0 = x @ Wp + bp ; init sync state ----------------
__global__ __launch_bounds__(128) void k_h0(const float* __restrict__ x,
                                            const float* __restrict__ Wp,
                                            const float* __restrict__ bp,
                                            float* __restrict__ h,
                                            bf16_t* __restrict__ h2hi,
                                            int* __restrict__ flags, int fs,
                                            int sent) {
  __shared__ float sx[8][IND];
  const int t  = threadIdx.x;      // 0..127 = output channel
  const int vb = blockIdx.x * 8;   // 8 nodes per block
  #pragma unroll
  for (int rr = 0; rr < 8; ++rr) sx[rr][t] = x[(size_t)(vb + rr) * IND + t];
  __syncthreads();
  float acc[8];
  const float bias = bp[t];
  #pragma unroll
  for (int rr = 0; rr < 8; ++rr) acc[rr] = bias;
  for (int k = 0; k < IND; ++k) {
    const float w = Wp[k * HID + t];
    #pragma unroll
    for (int rr = 0; rr < 8; ++rr) acc[rr] += sx[rr][k] * w;
  }
  #pragma unroll
  for (int rr = 0; rr < 8; ++rr) h[(size_t)(vb + rr) * HID + t] = acc[rr];
  if (sent) {
    // hi plane: row 0 = bf16 of h0 (node 0 final); rows >=1 = 0xFFFF sentinel
    #pragma unroll
    for (int rr = 0; rr < 8; ++rr) {
      unsigned short hw = 0xFFFFu;
      if (vb + rr == 0) hw = bfbits((bf16_t)acc[rr]);
      h2hi[(size_t)(vb + rr) * HID + t] = bits2bf(hw);
    }
  } else if (t < 8) {
    flags[(vb + t) * fs] = (vb + t == 0) ? 0xF : 0;
  }
}

// ---------------- kernel 2: persistent DAG executor ----------------
// 256 blocks (1/CU), 4 waves, each wave owns two ADJACENT channels per lane
// (cc = wid*32+2r, +1). Sync channel = planar bf16-hi rows: gathered 16B
// chunks ARE the MFMA A-fragments; sentinel = bf16 sign bits. On-chain
// phases use plain-bf16 weights (32 MFMAs/wave/node, issue-bound at ~19cy
// each on 1-wave/SIMD); weight-lo kept only off-chain (attr, u1-h0 half).
#define LOAD_WFRAGS(W, KROWS, NKK, ARRH, ARRL)                                \
  _Pragma("unroll")                                                           \
  for (int n = 0; n < 2; ++n) {                                               \
    _Pragma("unroll")                                                         \
    for (int kk = 0; kk < NKK; ++kk) {                                        \
      _Pragma("unroll")                                                       \
      for (int i = 0; i < 8; ++i) {                                           \
        const int k = kk * 32 + g * 8 + i;                                    \
        const float w = (k < KROWS) ? W[k * HID + cc[n]] : 0.f;               \
        const bf16_t wh = (bf16_t)w;                                          \
        ARRH[n][kk][i] = wh;                                                  \
        ARRL[n][kk][i] = (bf16_t)(w - (float)wh);                             \
      }                                                                       \
    }                                                                         \
  }
#define LOAD_WFRAGS_H(W, KROWS, NKK, ARRH)                                    \
  _Pragma("unroll")                                                           \
  for (int n = 0; n < 2; ++n) {                                               \
    _Pragma("unroll")                                                         \
    for (int kk = 0; kk < NKK; ++kk) {                                        \
      _Pragma("unroll")                                                       \
      for (int i = 0; i < 8; ++i) {                                           \
        const int k = kk * 32 + g * 8 + i;                                    \
        const float w = (k < KROWS) ? W[k * HID + cc[n]] : 0.f;               \
        ARRH[n][kk][i] = (bf16_t)w;                                           \
      }                                                                       \
    }                                                                         \
  }
#define LOAD_WFRAGS_L(W, KROWS, NKK, ARRL)                                    \
  _Pragma("unroll")                                                           \
  for (int n = 0; n < 2; ++n) {                                               \
    _Pragma("unroll")                                                         \
    for (int kk = 0; kk < NKK; ++kk) {                                        \
      _Pragma("unroll")                                                       \
      for (int i = 0; i < 8; ++i) {                                           \
        const int k = kk * 32 + g * 8 + i;                                    \
        const float w = (k < KROWS) ? W[k * HID + cc[n]] : 0.f;               \
        ARRL[n][kk][i] = (bf16_t)(w - (float)(bf16_t)w);                      \
      }                                                                       \
    }                                                                         \
  }

// SENT gather: 8 u64 relaxed-atomic loads of the hi plane (lane's quarter row)
#define LOADQH()                                                              \
  _Pragma("unroll")                                                           \
  for (int kk = 0; kk < 4; ++kk) {                                            \
    _Pragma("unroll")                                                         \
    for (int u = 0; u < 2; ++u)                                               \
      q[kk * 2 + u] = __hip_atomic_load(hp + kk * 8 + u, __ATOMIC_RELAXED,    \
                                        __HIP_MEMORY_SCOPE_AGENT);            \
  }

#define ZERO4(a) { a[0][0]=0.f;a[0][1]=0.f;a[0][2]=0.f;a[0][3]=0.f; a[1]=a[0]; }
#define BIAS4(a, b) { a[0][0]=b[0];a[0][1]=b[0];a[0][2]=b[0];a[0][3]=b[0];    \
                      a[1][0]=b[1];a[1][1]=b[1];a[1][2]=b[1];a[1][3]=b[1]; }

template <bool SENT>
__global__ __launch_bounds__(256, 1) void k_dag(
    const int* __restrict__ ei, const float* __restrict__ attr,
    const float* __restrict__ Wm1, const float* __restrict__ bm1,
    const float* __restrict__ Wm2, const float* __restrict__ bm2,
    const float* __restrict__ Wu1, const float* __restrict__ bu1,
    const float* __restrict__ Wu2, const float* __restrict__ bu2,
    float* __restrict__ h, bf16_t* __restrict__ h2hi,
    int* __restrict__ flags, int fs) {
  const int tid  = threadIdx.x;
  const int lane = tid & 63;
  const int g    = lane >> 4;   // 16-lane group: k-block of A/B operands
  const int r    = lane & 15;   // A-row / B-col within tile
  const int wid  = tid >> 6;    // wave 0..3

  __shared__ bf16_t s_m1[16 * HID];            // msg1 acts, chunk-XOR swizzled
  __shared__ alignas(16) bf16_t s_agg[HID];    // bf16: read directly as frags
  __shared__ alignas(16) bf16_t s_u1[HID];

  int cc[2];                     // two ADJACENT channels per lane
  cc[0] = wid * 32 + 2 * r;
  cc[1] = cc[0] + 1;

  // ---- register-resident weight fragments ----
  bf16x8 wm1h[2][5], wm1l4[2];            // m1: hi; weight-lo only for attr k-step
  bf16x8 wm2h[2][4];                      // m2: hi only
  bf16x8 wu1h[2][8], wu1l[2][4];          // u1: lo only for h-half (off-chain)
  bf16x8 wu2h[2][4];                      // u2: hi only
  LOAD_WFRAGS_H(Wm1, 136, 5, wm1h)        // rows 0..127 = h, 128..135 = attr
  #pragma unroll
  for (int n = 0; n < 2; ++n)
    #pragma unroll
    for (int i = 0; i < 8; ++i) {
      const int k = 128 + g * 8 + i;
      const float w = (k < 136) ? Wm1[k * HID + cc[n]] : 0.f;
      wm1l4[n][i] = (bf16_t)(w - (float)(bf16_t)w);
    }
  LOAD_WFRAGS_H(Wm2, 128, 4, wm2h)
  LOAD_WFRAGS_H(Wu1, 256, 8, wu1h)
  LOAD_WFRAGS_L(Wu1, 128, 4, wu1l)
  LOAD_WFRAGS_H(Wu2, 128, 4, wu2h)
  float bs_m1[2], bs_m2[2], bs_u1[2], bs_u2[2];
  #pragma unroll
  for (int n = 0; n < 2; ++n) {
    bs_m1[n] = bm1[cc[n]]; bs_m2[n] = bm2[cc[n]];
    bs_u1[n] = bu1[cc[n]]; bs_u2[n] = bu2[cc[n]];
  }

  const int v0 = 1 + (int)blockIdx.x;
  int s_cur = (v0 < NN) ? ei[(v0 - 1) * DEG + r] : 0;

  for (int v = v0; v < NN; v += NBLK) {
    // ---- poll/gather loads issue FIRST (minimize detect phase delay) ----
    u64 q[16];  // SENT uses [0..7] (hi plane); fallback uses all 16 (fp32 row)
    const u64* hp;
    if constexpr (SENT) {
      hp = (const u64*)(h2hi + (size_t)s_cur * HID) + g * 2;  // 32 u64/row
      LOADQH();
    } else {
      hp = (const u64*)(h + (size_t)s_cur * HID) + g * 4;
      #pragma unroll
      for (int kk = 0; kk < 4; ++kk)
        #pragma unroll
        for (int u = 0; u < 4; ++u)
          q[kk * 4 + u] = __hip_atomic_load(hp + kk * 16 + u, __ATOMIC_RELAXED,
                                            __HIP_MEMORY_SCOPE_AGENT);
    }

    // ---- off-chain: next edge list, own h0 row -> fragments, attr frag ----
    const int vn = (v + NBLK < NN) ? v + NBLK : v;
    const int s_nxt = ei[(vn - 1) * DEG + r];

    bf16x8 hvh[4], hvl[4];
    {
      const float* hvp = h + (size_t)v * HID + g * 8;
      #pragma unroll
      for (int kk = 0; kk < 4; ++kk) {
        const f32x4 p0 = *(const f32x4*)(hvp + kk * 32);
        const f32x4 p1 = *(const f32x4*)(hvp + kk * 32 + 4);
        #pragma unroll
        for (int i = 0; i < 4; ++i) {
          const float f0 = p0[i], f1 = p1[i];
          const bf16_t f0h = (bf16_t)f0, f1h = (bf16_t)f1;
          hvh[kk][i]     = f0h; hvl[kk][i]     = (bf16_t)(f0 - (float)f0h);
          hvh[kk][4 + i] = f1h; hvl[kk][4 + i] = (bf16_t)(f1 - (float)f1h);
        }
      }
    }
    bf16x8 a4h;
    #pragma unroll
    for (int i = 0; i < 8; ++i) a4h[i] = (bf16_t)0.f;
    if (g == 0) {
      const f32x4* ap = (const f32x4*)(attr + ((size_t)(v - 1) * DEG + r) * ED);
      const f32x4 a0 = ap[0], a1 = ap[1];
      #pragma unroll
      for (int i = 0; i < 4; ++i) {
        a4h[i] = (bf16_t)a0[i]; a4h[4 + i] = (bf16_t)a1[i];
      }
    }

    // ---- off-chain MFMA work overlapping the in-flight poll loads ----
    // (a) u1 h0_v-half (hi + weight-lo + act-lo; off-chain so depth is free)
    f32x4 uA[2], uB[2], uC[2], uD[2];
    BIAS4(uA, bs_u1) ZERO4(uB) ZERO4(uC) ZERO4(uD)
    #pragma unroll
    for (int kk = 0; kk < 4; ++kk) {
      #pragma unroll
      for (int n = 0; n < 2; ++n) {
        uA[n] = mfma16(hvh[kk], wu1h[n][kk], uA[n]);
        uB[n] = mfma16(hvh[kk], wu1l[n][kk], uB[n]);
        uC[n] = mfma16(hvl[kk], wu1h[n][kk], uC[n]);
      }
    }
    // (b) m1 init + attr k-step (independent of preds); 4 accumulators so the
    // post-detect pred k-steps are depth-1
    f32x4 mA[2], mB[2], mC[2], mD[2];
    BIAS4(mA, bs_m1) ZERO4(mB) ZERO4(mC) ZERO4(mD)
    #pragma unroll
    for (int n = 0; n < 2; ++n) {
      mA[n] = mfma16(a4h, wm1h[n][4], mA[n]);
      mB[n] = mfma16(a4h, wm1l4[n], mB[n]);
    }

    // ---- spin: data IS the sync (bf16 sign bits = sentinel) ----
    if constexpr (SENT) {
      bool ok = false;
      int guard = 0;
      for (;;) {
        if (!ok) {
          u64 m = 0;
          #pragma unroll
          for (int i = 0; i < 8; ++i) m |= q[i];
          ok = (s_cur == 0) || ((m & 0x8000800080008000ull) == 0);
        }
        if (__all(ok)) break;
        if (++guard > (1 << 13)) break;  // fail-safe: wrong answer, never hang
        if (!ok) LOADQH();
      }
    } else {
      const int* fp = flags + s_cur * fs;
      int fw = __hip_atomic_load(fp, __ATOMIC_RELAXED, __HIP_MEMORY_SCOPE_AGENT);
      int guard = 0;
      while (fw != 0xF && ++guard < (1 << 15)) {
        __builtin_amdgcn_s_sleep(1);
        fw = __hip_atomic_load(fp, __ATOMIC_RELAXED, __HIP_MEMORY_SCOPE_AGENT);
      }
      asm volatile("" ::: "memory");
      #pragma unroll
      for (int kk = 0; kk < 4; ++kk)
        #pragma unroll
        for (int u = 0; u < 4; ++u)
          q[kk * 4 + u] = __hip_atomic_load(hp + kk * 16 + u, __ATOMIC_RELAXED,
                                            __HIP_MEMORY_SCOPE_AGENT);
    }

    // ---- A fragments: SENT = loaded 16B chunks verbatim (zero unpack) ----
    bf16x8 ah[4];
    #pragma unroll
    for (int kk = 0; kk < 4; ++kk) {
      if constexpr (SENT) {
        u64x2 t2; t2[0] = q[kk * 2]; t2[1] = q[kk * 2 + 1];
        ah[kk] = __builtin_bit_cast(bf16x8, t2);
      } else {
        #pragma unroll
        for (int u = 0; u < 4; ++u)
          #pragma unroll
          for (int b = 0; b < 2; ++b)
            ah[kk][u * 2 + b] =
                (bf16_t)__uint_as_float((unsigned)(q[kk * 4 + u] >> (32 * b)));
      }
    }

    // ---- msg layer 1: 4 pred k-steps (hi-only), depth-1 ----
    f32x4 m1[2];
    #pragma unroll
    for (int n = 0; n < 2; ++n) {
      mA[n] = mfma16(ah[0], wm1h[n][0], mA[n]);
      mB[n] = mfma16(ah[1], wm1h[n][1], mB[n]);
      mC[n] = mfma16(ah[2], wm1h[n][2], mC[n]);
      mD[n] = mfma16(ah[3], wm1h[n][3], mD[n]);
    }
    #pragma unroll
    for (int n = 0; n < 2; ++n)
      m1[n] = (mA[n] + mB[n]) + (mC[n] + mD[n]);
    // relu -> bf16 -> LDS with chunk-XOR swizzle (conflict-free b128 reads)
    #pragma unroll
    for (int n = 0; n < 2; ++n) {
      const int c = cc[n], ch16 = c >> 3;
      #pragma unroll
      for (int reg = 0; reg < 4; ++reg) {
        const int j = g * 4 + reg;  // edge row (D layout: row = 4*(lane>>4)+reg)
        s_m1[j * HID + ((ch16 ^ j) * 8) + (c & 7)] = (bf16_t)fmaxf(m1[n][reg], 0.f);
      }
    }
    if constexpr (SENT) bar_lds(); else __syncthreads();   // B1

    // ---- msg layer 2 (hi-only, depth-1) + mean aggregation ----
    f32x4 m2[2];
    {
      f32x4 aA[2], aB[2], aC[2], aD[2];
      BIAS4(aA, bs_m2) ZERO4(aB) ZERO4(aC) ZERO4(aD)
      const bf16x8 a0 = *(const bf16x8*)(s_m1 + r * HID + (((0 * 4 + g) ^ r) * 8));
      const bf16x8 a1 = *(const bf16x8*)(s_m1 + r * HID + (((1 * 4 + g) ^ r) * 8));
      const bf16x8 a2 = *(const bf16x8*)(s_m1 + r * HID + (((2 * 4 + g) ^ r) * 8));
      const bf16x8 a3 = *(const bf16x8*)(s_m1 + r * HID + (((3 * 4 + g) ^ r) * 8));
      #pragma unroll
      for (int n = 0; n < 2; ++n) {
        aA[n] = mfma16(a0, wm2h[n][0], aA[n]);
        aB[n] = mfma16(a1, wm2h[n][1], aB[n]);
        aC[n] = mfma16(a2, wm2h[n][2], aC[n]);
        aD[n] = mfma16(a3, wm2h[n][3], aD[n]);
      }
      #pragma unroll
      for (int n = 0; n < 2; ++n) m2[n] = (aA[n] + aB[n]) + (aC[n] + aD[n]);
    }
    #pragma unroll
    for (int n = 0; n < 2; ++n) {
      float s = fmaxf(m2[n][0],0.f)+fmaxf(m2[n][1],0.f)+fmaxf(m2[n][2],0.f)+fmaxf(m2[n][3],0.f);
      s += __shfl_xor(s, 16, 64);
      s += __shfl_xor(s, 32, 64);
      if (lane < 16) s_agg[cc[n]] = (bf16_t)(s * 0.0625f);  // bf16 once
    }
    if constexpr (SENT) bar_lds(); else __syncthreads();   // B2

    // ---- update layer 1, agg-half (hi-only, depth-1: kk4..7 -> uA..uD) ----
    f32x4 u1v[2];
    {
      const bf16x8 A0 = *(const bf16x8*)(s_agg + 0 * 32 + g * 8);
      const bf16x8 A1 = *(const bf16x8*)(s_agg + 1 * 32 + g * 8);
      const bf16x8 A2 = *(const bf16x8*)(s_agg + 2 * 32 + g * 8);
      const bf16x8 A3 = *(const bf16x8*)(s_agg + 3 * 32 + g * 8);
      #pragma unroll
      for (int n = 0; n < 2; ++n) {
        uA[n] = mfma16(A0, wu1h[n][4], uA[n]);
        uB[n] = mfma16(A1, wu1h[n][5], uB[n]);
        uC[n] = mfma16(A2, wu1h[n][6], uC[n]);
        uD[n] = mfma16(A3, wu1h[n][7], uD[n]);
      }
    }
    #pragma unroll
    for (int n = 0; n < 2; ++n)
      u1v[n] = (uA[n] + uB[n]) + (uC[n] + uD[n]);
    if (lane < 16) {
      s_u1[cc[0]] = (bf16_t)fmaxf(u1v[0][0], 0.f);
      s_u1[cc[1]] = (bf16_t)fmaxf(u1v[1][0], 0.f);
    }
    if constexpr (SENT) bar_lds(); else __syncthreads();   // B3

    // ---- update layer 2 (hi-only, depth-1) -> publish ----
    f32x4 u2v[2];
    {
      f32x4 aA[2], aB[2], aC[2], aD[2];
      BIAS4(aA, bs_u2) ZERO4(aB) ZERO4(aC) ZERO4(aD)
      const bf16x8 A0 = *(const bf16x8*)(s_u1 + 0 * 32 + g * 8);
      const bf16x8 A1 = *(const bf16x8*)(s_u1 + 1 * 32 + g * 8);
      const bf16x8 A2 = *(const bf16x8*)(s_u1 + 2 * 32 + g * 8);
      const bf16x8 A3 = *(const bf16x8*)(s_u1 + 3 * 32 + g * 8);
      #pragma unroll
      for (int n = 0; n < 2; ++n) {
        aA[n] = mfma16(A0, wu2h[n][0], aA[n]);
        aB[n] = mfma16(A1, wu2h[n][1], aB[n]);
        aC[n] = mfma16(A2, wu2h[n][2], aC[n]);
        aD[n] = mfma16(A3, wu2h[n][3], aD[n]);
      }
      #pragma unroll
      for (int n = 0; n < 2; ++n)
        u2v[n] = (aA[n] + aB[n]) + (aC[n] + aD[n]);
    }
    if (lane < 16) {  // D row 0 (all rows identical)
      const float r0 = fabsf(fmaxf(u2v[0][0], 0.f));  // fabs: kill -0.0
      const float r1 = fabsf(fmaxf(u2v[1][0], 0.f));
      if constexpr (SENT) {
        // hi-plane sync store FIRST (it gates consumers)
        const unsigned hiw = (unsigned)bfbits((bf16_t)r0) |
                             ((unsigned)bfbits((bf16_t)r1) << 16);
        __hip_atomic_store((unsigned*)h2hi + (size_t)v * (HID / 2) + wid * 16 + r,
                           hiw, __ATOMIC_RELAXED, __HIP_MEMORY_SCOPE_AGENT);
        // fp32 output store (plain, off the sync path)
        f32x2 out2; out2[0] = r0; out2[1] = r1;
        *(f32x2*)&h[(size_t)v * HID + cc[0]] = out2;
      } else {
        __hip_atomic_store(&h[(size_t)v * HID + cc[0]], r0,
                           __ATOMIC_RELAXED, __HIP_MEMORY_SCOPE_AGENT);
        __hip_atomic_store(&h[(size_t)v * HID + cc[1]], r1,
                           __ATOMIC_RELAXED, __HIP_MEMORY_SCOPE_AGENT);
      }
    }
    if constexpr (!SENT) {
      if (lane == 0)
        __hip_atomic_fetch_or(&flags[v * fs], 1 << wid, __ATOMIC_RELEASE,
                              __HIP_MEMORY_SCOPE_AGENT);
    }
    s_cur = s_nxt;
    if constexpr (!SENT) __syncthreads();
  }
}

extern "C" void kernel_launch(void* const* d_in, const int* in_sizes, int n_in,
                              void* d_out, int out_size, void* d_ws, size_t ws_size,
                              hipStream_t stream) {
  const float* x    = (const float*)d_in[0];
  const int*   ei   = (const int*)  d_in[1];   // [2, E] int32; row 0 = src
  const float* attr = (const float*)d_in[2];
  const float* Wp   = (const float*)d_in[3];
  const float* bp   = (const float*)d_in[4];
  const float* Wm1  = (const float*)d_in[5];
  const float* bm1  = (const float*)d_in[6];
  const float* Wm2  = (const float*)d_in[7];
  const float* bm2  = (const float*)d_in[8];
  const float* Wu1  = (const float*)d_in[9];
  const float* bu1  = (const float*)d_in[10];
  const float* Wu2  = (const float*)d_in[11];
  const float* bu2  = (const float*)d_in[12];
  float* h = (float*)d_out;   // h state lives directly in d_out

  const size_t plane = (size_t)NN * HID * sizeof(bf16_t);   // 2 MB
  const bool sent = ws_size >= plane;
  bf16_t* h2hi = (bf16_t*)d_ws;
  int* flags   = (int*)d_ws;
  const int fs = sent ? 0 : ((ws_size >= (size_t)NN * 64 + 64) ? 16 : 1);

  k_h0<<<NN / 8, 128, 0, stream>>>(x, Wp, bp, h, h2hi, flags, fs, sent ? 1 : 0);
  if (sent)
    k_dag<true><<<NBLK, 256, 0, stream>>>(ei, attr, Wm1, bm1, Wm2, bm2,
                                          Wu1, bu1, Wu2, bu2, h, h2hi,
                                          flags, fs);
  else
    k_dag<false><<<NBLK, 256, 0, stream>>>(ei, attr, Wm1, bm1, Wm2, bm2,
                                           Wu1, bu1, Wu2, bu2, h, h2hi,
                                           flags, fs);
}